// Round 8
// baseline (451.861 us; speedup 1.0000x reference)
//
#include <hip/hip_runtime.h>
#include <math.h>

// Problem constants (DeformConv_68109591380935) — ALL TENSORS FLOAT32
#define BN_    4
#define CHI_   256
#define CHO_   256
#define HH_    96
#define WW_    96
#define HW_    (HH_*WW_)        // 9216
#define KK_    9
#define CK_    (CHI_*KK_)       // 2304
#define NRED_  (BN_*HW_)        // 36864 samples per BN channel
#define BN_EPS_ 1e-5f

// R8: deform_fused split along oc: 128 oc x 64 px per block, grid 1152
// (4-5 blocks/CU). oc-halves of the same pixel tile adjacent on same XCD
// (xt reads shared via L2). Chunk = 1 tap x 64 ch (kk-major W). B-stage =
// coalesced channels-last gather (R6/R7-proven math).

// offset_mfma tiling: 32 oc (27 + 5 zero) x 64 px, KC 96 (UNCHANGED)
#define OTPX_   64
#define OKC_    96
#define OPITCH_ 104             // 208B rows (known-good class)

typedef short short8 __attribute__((ext_vector_type(8)));
typedef float f32x4  __attribute__((ext_vector_type(4)));

// round-to-nearest-even f32 -> bf16 bit pattern
__device__ __forceinline__ unsigned short f2bf(float v) {
    union { float f; unsigned u; } c; c.f = v;
    unsigned lsb = (c.u >> 16) & 1u;
    c.u += 0x7fffu + lsb;
    return (unsigned short)(c.u >> 16);
}

// ---------------------------------------------------------------------------
// Kernel 0a: w_conv f32 -> bf16 with K-dim permutation (c,k) -> (k,c).
//   wb2[o][k*256 + c] = bf16(w[o][c*9 + k])
// ---------------------------------------------------------------------------
__global__ __launch_bounds__(256) void w2b_perm(
    const float* __restrict__ w, unsigned short* __restrict__ wb)
{
    int idx = blockIdx.x * 256 + threadIdx.x;     // o*2304 + k*256 + c
    int o  = idx / CK_;
    int kk = idx - o * CK_;
    int k  = kk >> 8;
    int c  = kk & 255;
    wb[idx] = f2bf(w[o * CK_ + c * KK_ + k]);
}

// ---------------------------------------------------------------------------
// Kernel 0b: plain f32 -> bf16 convert (w_offset)
// ---------------------------------------------------------------------------
__global__ __launch_bounds__(256) void w2b(
    const float* __restrict__ w, unsigned short* __restrict__ wb)
{
    int idx = blockIdx.x * 256 + threadIdx.x;
    wb[idx] = f2bf(w[idx]);
}

// ---------------------------------------------------------------------------
// Kernel 0c: NCHW -> NHWC transpose of x.  xt[b][p][c] = x[b][c][p]
// ---------------------------------------------------------------------------
__global__ __launch_bounds__(256) void transpose_x(
    const float* __restrict__ x, float* __restrict__ xt)
{
    __shared__ float tile[64][65];
    const int t = threadIdx.x;
    const int bid = blockIdx.x;
    const int b  = bid / (144 * 4);
    const int r  = bid - b * 576;
    const int pt = r >> 2, ct = r & 3;
    const int p0 = pt * 64, c0 = ct * 64;

    const int px = t & 63, g = t >> 6;
#pragma unroll
    for (int i = 0; i < 16; i++) {
        int cr = g + i * 4;
        tile[cr][px] = x[((size_t)b * CHI_ + c0 + cr) * HW_ + p0 + px];
    }
    __syncthreads();
    const int c = t & 63;
#pragma unroll
    for (int i = 0; i < 16; i++) {
        int pr = g + i * 4;
        xt[((size_t)b * HW_ + p0 + pr) * CHI_ + c0 + c] = tile[c][pr];
    }
}

// ---------------------------------------------------------------------------
// Kernel 1: offset conv as MFMA GEMM (UNCHANGED from known-good baseline).
// ---------------------------------------------------------------------------
__global__ __launch_bounds__(256) void offset_mfma(
    const float* __restrict__ x, const unsigned short* __restrict__ wob,
    const float* __restrict__ bo, float* __restrict__ om)
{
    __shared__ __align__(16) unsigned short s_w[32 * OPITCH_];     //  6656 B
    __shared__ __align__(16) unsigned short s_cols[OTPX_ * OPITCH_];// 13312 B

    const int t = threadIdx.x;
    const int pixtile = blockIdx.x % (HW_ / OTPX_);  // 144
    const int b       = blockIdx.x / (HW_ / OTPX_);  // 4
    const int p0 = pixtile * OTPX_;

    const int lane = t & 63, wave = t >> 6;
    const int quad = lane >> 4, l15 = lane & 15;

    const int i   = t & 63;            // pixel within tile (staging role)
    const int jlb = (t >> 6) * 24;     // k-subrange within chunk
    const int p   = p0 + i;
    const int h   = p / WW_, w = p % WW_;
    const float* xb = x + (size_t)b * CHI_ * HW_;

    f32x4 acc[2];
    acc[0] = (f32x4){0.f,0.f,0.f,0.f};
    acc[1] = (f32x4){0.f,0.f,0.f,0.f};

    for (int kc = 0; kc < CK_ / OKC_; kc++) {        // 24 chunks
        const int j0 = kc * OKC_;
        if (kc) __syncthreads();
#pragma unroll
        for (int n = 0; n < 3; n++) {
            int e = t + n * 256;                     // < 768
            int ocl = e / 24, kq = e % 24;
            uint2 v = make_uint2(0u, 0u);
            if (ocl < 27)
                v = *reinterpret_cast<const uint2*>(wob + (size_t)ocl * CK_ + j0 + kq * 4);
            *reinterpret_cast<uint2*>(&s_w[ocl * OPITCH_ + kq * 4]) = v;
        }
        union { unsigned short s[24]; uint4 q[3]; } pk;
#pragma unroll
        for (int m = 0; m < 24; m++) {
            int jg = j0 + jlb + m;
            int c  = (jg * 7282) >> 16;              // jg/9
            int k  = jg - 9 * c;
            int yy = h + k / 3 - 1, xx = w + k % 3 - 1;
            bool ok = ((unsigned)yy < HH_) & ((unsigned)xx < WW_);
            float v = ok ? xb[(size_t)c * HW_ + yy * WW_ + xx] : 0.f;
            pk.s[m] = f2bf(v);
        }
        {
            uint4* dst = reinterpret_cast<uint4*>(&s_cols[i * OPITCH_ + jlb]);
            dst[0] = pk.q[0]; dst[1] = pk.q[1]; dst[2] = pk.q[2];
        }
        __syncthreads();
#pragma unroll
        for (int ks = 0; ks < OKC_ / 32; ks++) {
            short8 a0 = *reinterpret_cast<const short8*>(
                &s_w[(l15) * OPITCH_ + ks * 32 + quad * 8]);
            short8 a1 = *reinterpret_cast<const short8*>(
                &s_w[(16 + l15) * OPITCH_ + ks * 32 + quad * 8]);
            short8 b0 = *reinterpret_cast<const short8*>(
                &s_cols[(wave * 16 + l15) * OPITCH_ + ks * 32 + quad * 8]);
            acc[0] = __builtin_amdgcn_mfma_f32_16x16x32_bf16(a0, b0, acc[0], 0, 0, 0);
            acc[1] = __builtin_amdgcn_mfma_f32_16x16x32_bf16(a1, b0, acc[1], 0, 0, 0);
        }
    }

#pragma unroll
    for (int mt = 0; mt < 2; mt++) {
#pragma unroll
        for (int r = 0; r < 4; r++) {
            int oc = mt * 16 + quad * 4 + r;
            if (oc < 27) {
                int pix = p0 + wave * 16 + l15;
                om[((size_t)b * 27 + oc) * HW_ + pix] = acc[mt][r] + bo[oc];
            }
        }
    }
}

// ---------------------------------------------------------------------------
// Kernel 2: fused channels-last gather + bf16 MFMA GEMM (oc-split).
//   Block: 128 oc x 64 px, 1152 blocks. Chunk kc (36) = tap kc>>2, 64 ch.
//   u = xcd*144+local; oh = u&1 (oc half), tile = u>>1 -> oc-halves of the
//   same pixel tile are adjacent on one XCD (shared xt reads hit L2).
// ---------------------------------------------------------------------------
__global__ __launch_bounds__(256, 4) void deform_fused(
    const float* __restrict__ xt, const float* __restrict__ om,
    const unsigned short* __restrict__ wb, const float* __restrict__ bconv,
    float* __restrict__ outb)
{
    __shared__ __align__(16) unsigned short sA[128 * 64];    // 16384 B (swizzled)
    __shared__ __align__(16) unsigned short sB[64 * 64];     //  8192 B (swizzled)
    __shared__ float s_py[KK_ * 64], s_px[KK_ * 64], s_mask[KK_ * 64]; // 6912 B

    const int t = threadIdx.x;
    // XCD-aware: 1152 = 8 XCDs x 144 units; unit -> (oc-half, pixel tile)
    const int bid = blockIdx.x;
    const int u   = (bid & 7) * 144 + (bid >> 3);    // [0,1152)
    const int oh  = u & 1;                           // oc half 0/1
    const int j   = u >> 1;                          // [0,576)
    const int pixtile = j % 144;
    const int b       = j / 144;
    const int p0 = pixtile * 64;
    const int o0 = oh * 128;

    // ---- meta: py/px/mask for 9 taps x 64 pixels (once per block) ----
    for (int e = t; e < KK_ * 64; e += 256) {
        int k = e >> 6, i = e & 63;
        int p = p0 + i;
        int h = p / WW_, w = p % WW_;
        const float* omb = om + ((size_t)b * 27) * HW_ + p;
        float dy = omb[(2 * k) * HW_];
        float dx = omb[(2 * k + 1) * HW_];
        float m  = omb[(18 + k) * HW_];
        s_py[e]   = dy + (float)(h + k / 3 - 1);
        s_px[e]   = dx + (float)(w + (k % 3) - 1);
        s_mask[e] = 1.f / (1.f + __expf(-m));
    }

    const int lane = t & 63, wave = t >> 6;
    const int quad = lane >> 4, l15 = lane & 15;
    const int pxl  = t >> 2;           // gather role: pixel 0..63
    const int cg   = t & 3;            // gather role: 16-ch group

    f32x4 acc[2][4];
#pragma unroll
    for (int m = 0; m < 2; m++)
#pragma unroll
        for (int n = 0; n < 4; n++)
            acc[m][n] = (f32x4){0.f, 0.f, 0.f, 0.f};

    const float* xtb = xt + (size_t)b * HW_ * CHI_;
    char* sAb = (char*)sA;
    char* sBb = (char*)sB;

    __syncthreads();   // meta visible

    for (int kc = 0; kc < 36; kc++) {
        const int j0 = kc * 64;
        if (kc) __syncthreads();
        // ---- stage A (W'): 128 oc x 64 kk, 4 x uint4 per thread, swizzled
#pragma unroll
        for (int n = 0; n < 4; n++) {
            int e = t + n * 256;                   // < 1024
            int ocl = e >> 3, ko = e & 7;
            uint4 v = *reinterpret_cast<const uint4*>(
                wb + (size_t)(o0 + ocl) * CK_ + j0 + ko * 8);
            *reinterpret_cast<uint4*>(
                sAb + (ocl << 7) + ((ko << 4) ^ ((ocl & 7) << 4))) = v;
        }
        // ---- stage B: gather 64 px x 64 ch for tap k (coalesced) ----
        {
            const int k  = kc >> 2;
            const int c0 = (kc & 3) << 6;
            const int e  = k * 64 + pxl;
            float py = s_py[e], pxx = s_px[e], msk = s_mask[e];
            float y0f = floorf(py), x0f = floorf(pxx);
            float ly = py - y0f, lx = pxx - x0f;
            int y0 = (int)y0f, x0 = (int)x0f;
            float vy0 = ((unsigned)y0       < HH_) ? 1.f : 0.f;
            float vy1 = ((unsigned)(y0 + 1) < HH_) ? 1.f : 0.f;
            float vx0 = ((unsigned)x0       < WW_) ? 1.f : 0.f;
            float vx1 = ((unsigned)(x0 + 1) < WW_) ? 1.f : 0.f;
            int yc0 = min(max(y0, 0), HH_ - 1), yc1 = min(max(y0 + 1, 0), HH_ - 1);
            int xc0 = min(max(x0, 0), WW_ - 1), xc1 = min(max(x0 + 1, 0), WW_ - 1);
            float wy0 = 1.f - ly, wx0 = 1.f - lx;
            float w00 = wy0 * wx0 * vy0 * vx0 * msk;
            float w01 = wy0 * lx  * vy0 * vx1 * msk;
            float w10 = ly  * wx0 * vy1 * vx0 * msk;
            float w11 = ly  * lx  * vy1 * vx1 * msk;
            const float* base = xtb + c0 + cg * 16;
            const float4* r00 = reinterpret_cast<const float4*>(
                base + (size_t)(yc0 * WW_ + xc0) * CHI_);
            const float4* r01 = reinterpret_cast<const float4*>(
                base + (size_t)(yc0 * WW_ + xc1) * CHI_);
            const float4* r10 = reinterpret_cast<const float4*>(
                base + (size_t)(yc1 * WW_ + xc0) * CHI_);
            const float4* r11 = reinterpret_cast<const float4*>(
                base + (size_t)(yc1 * WW_ + xc1) * CHI_);
            union { unsigned short s[16]; uint4 q[2]; } pk;
#pragma unroll
            for (int i = 0; i < 4; i++) {
                float4 fa = r00[i], fb = r01[i], fc = r10[i], fd = r11[i];
                pk.s[i * 4 + 0] = f2bf(fa.x * w00 + fb.x * w01 + fc.x * w10 + fd.x * w11);
                pk.s[i * 4 + 1] = f2bf(fa.y * w00 + fb.y * w01 + fc.y * w10 + fd.y * w11);
                pk.s[i * 4 + 2] = f2bf(fa.z * w00 + fb.z * w01 + fc.z * w10 + fd.z * w11);
                pk.s[i * 4 + 3] = f2bf(fa.w * w00 + fb.w * w01 + fc.w * w10 + fd.w * w11);
            }
            const int u0 = cg << 1;                // 16B-unit col index
            *reinterpret_cast<uint4*>(
                sBb + (pxl << 7) + ((u0 << 4) ^ ((pxl & 7) << 4))) = pk.q[0];
            *reinterpret_cast<uint4*>(
                sBb + (pxl << 7) + (((u0 + 1) << 4) ^ ((pxl & 7) << 4))) = pk.q[1];
        }
        __syncthreads();
        // ---- MFMA: 2 K-steps of 32; wave = 32-oc slice, full 64 px ----
#pragma unroll
        for (int ks = 0; ks < 2; ks++) {
            short8 afr[2], bfr[4];
#pragma unroll
            for (int m = 0; m < 2; m++) {
                int r = wave * 32 + m * 16 + l15;
                afr[m] = *reinterpret_cast<const short8*>(
                    sAb + (r << 7) + (((ks << 6) + (quad << 4)) ^ ((r & 7) << 4)));
            }
#pragma unroll
            for (int n = 0; n < 4; n++) {
                int r = n * 16 + l15;
                bfr[n] = *reinterpret_cast<const short8*>(
                    sBb + (r << 7) + (((ks << 6) + (quad << 4)) ^ ((r & 7) << 4)));
            }
#pragma unroll
            for (int m = 0; m < 2; m++)
#pragma unroll
                for (int n = 0; n < 4; n++)
                    acc[m][n] = __builtin_amdgcn_mfma_f32_16x16x32_bf16(
                        afr[m], bfr[n], acc[m][n], 0, 0, 0);
        }
    }

    // ---- epilogue: C/D layout col=lane&15 (pixel), row=quad*4+r (oc) ----
#pragma unroll
    for (int m = 0; m < 2; m++) {
#pragma unroll
        for (int n = 0; n < 4; n++) {
#pragma unroll
            for (int r = 0; r < 4; r++) {
                int oc  = o0 + wave * 32 + m * 16 + quad * 4 + r;
                int pix = p0 + n * 16 + l15;
                outb[((size_t)b * CHO_ + oc) * HW_ + pix] = acc[m][n][r] + bconv[oc];
            }
        }
    }
}

// ---------------------------------------------------------------------------
// Kernel 3: BN statistics (sum, sumsq) per channel, deterministic two-pass
// ---------------------------------------------------------------------------
__global__ __launch_bounds__(256) void bn_stats(
    const float* __restrict__ outb, float* __restrict__ stats)
{
    int o = blockIdx.x, t = threadIdx.x;
    float s = 0.f, s2 = 0.f;
    for (int b = 0; b < BN_; b++) {
        const float* base = outb + ((size_t)b * CHO_ + o) * HW_;
        for (int p = t; p < HW_; p += 256) {
            float v = base[p];
            s += v; s2 += v * v;
        }
    }
#pragma unroll
    for (int off = 32; off > 0; off >>= 1) {
        s  += __shfl_down(s,  off, 64);
        s2 += __shfl_down(s2, off, 64);
    }
    __shared__ float rs[4], rs2[4];
    int lane = t & 63, wv = t >> 6;
    if (lane == 0) { rs[wv] = s; rs2[wv] = s2; }
    __syncthreads();
    if (t == 0) {
        stats[o]        = rs[0] + rs[1] + rs[2] + rs[3];
        stats[CHO_ + o] = rs2[0] + rs2[1] + rs2[2] + rs2[3];
    }
}

// ---------------------------------------------------------------------------
// Kernel 4: BN apply + ReLU, f32 out
// ---------------------------------------------------------------------------
__global__ __launch_bounds__(256) void bn_apply(
    const float* __restrict__ outb, const float* __restrict__ stats,
    const float* __restrict__ gamma, const float* __restrict__ beta,
    float* __restrict__ y)
{
    int idx = blockIdx.x * 256 + threadIdx.x;
    size_t i0 = (size_t)idx * 4;                  // < 9437184
    int o = (int)((i0 / HW_) % CHO_);
    float4 v = *reinterpret_cast<const float4*>(outb + i0);
    const float invN = 1.f / (float)NRED_;
    float mu  = stats[o] * invN;
    float var = stats[CHO_ + o] * invN - mu * mu;
    float inv = rsqrtf(var + BN_EPS_);
    float sc = gamma[o] * inv;
    float sh = beta[o] - mu * sc;
    float4 r;
    r.x = fmaxf(v.x * sc + sh, 0.f);
    r.y = fmaxf(v.y * sc + sh, 0.f);
    r.z = fmaxf(v.z * sc + sh, 0.f);
    r.w = fmaxf(v.w * sc + sh, 0.f);
    *reinterpret_cast<float4*>(y + i0) = r;
}

// ---------------------------------------------------------------------------
extern "C" void kernel_launch(void* const* d_in, const int* in_sizes, int n_in,
                              void* d_out, int out_size, void* d_ws, size_t ws_size,
                              hipStream_t stream)
{
    const float* x   = (const float*)d_in[0];
    const float* wof = (const float*)d_in[1];
    const float* bof = (const float*)d_in[2];
    const float* wcv = (const float*)d_in[3];
    const float* bcv = (const float*)d_in[4];
    const float* gam = (const float*)d_in[5];
    const float* bet = (const float*)d_in[6];
    float* y = (float*)d_out;

    char* ws = (char*)d_ws;
    float*          om    = (float*)ws;                                   // 3.98 MB
    float*          outb  = (float*)(ws + (size_t)4 * 1024 * 1024);       // 36 MB
    float*          stats = (float*)(ws + (size_t)40 * 1024 * 1024);      // 2 KB
    unsigned short* wbf2  = (unsigned short*)(ws + (size_t)40 * 1024 * 1024 + 8192);            // 1.125 MB
    unsigned short* wob   = (unsigned short*)(ws + (size_t)40 * 1024 * 1024 + 8192 + 1179648);  // 121.5 KB
    float*          xt    = (float*)(ws + (size_t)44 * 1024 * 1024);      // 37.75 MB

    w2b_perm<<<(CHO_ * CK_) / 256, 256, 0, stream>>>(wcv, wbf2);  // 2304 blocks
    w2b<<<(27 * CK_) / 256, 256, 0, stream>>>(wof, wob);          // 243 blocks
    transpose_x<<<BN_ * 144 * 4, 256, 0, stream>>>(x, xt);        // 2304 blocks
    offset_mfma<<<BN_ * (HW_ / OTPX_), 256, 0, stream>>>(x, wob, bof, om);
    deform_fused<<<BN_ * 2 * (HW_ / 64), 256, 0, stream>>>(xt, om, wbf2, bcv, outb);
    bn_stats<<<CHO_, 256, 0, stream>>>(outb, stats);
    bn_apply<<<(BN_ * CHO_ * HW_) / (4 * 256), 256, 0, stream>>>(outb, stats, gam, bet, y);
}

// Round 10
// 360.742 us; speedup vs baseline: 1.2526x; 1.2526x over previous
//
#include <hip/hip_runtime.h>
#include <math.h>

// Problem constants (DeformConv_68109591380935) — ALL TENSORS FLOAT32
#define BN_    4
#define CHI_   256
#define CHO_   256
#define HH_    96
#define WW_    96
#define HW_    (HH_*WW_)        // 9216
#define KK_    9
#define CK_    (CHI_*KK_)       // 2304
#define NRED_  (BN_*HW_)        // 36864 samples per BN channel
#define BN_EPS_ 1e-5f

// R9: R7 structure, split along PIXELS: 256 oc x 32 px per block, grid 1152.
// Gather exactly partitioned (no duplication); only W A-stage duplicated
// (L2-resident). Chunk = 1 tap x 64 ch (kk-major W). 40320 B LDS -> 4/CU.

// offset_mfma tiling: 32 oc (27 + 5 zero) x 64 px, KC 96 (UNCHANGED)
#define OTPX_   64
#define OKC_    96
#define OPITCH_ 104             // 208B rows (known-good class)

typedef short short8 __attribute__((ext_vector_type(8)));
typedef float f32x4  __attribute__((ext_vector_type(4)));

// round-to-nearest-even f32 -> bf16 bit pattern
__device__ __forceinline__ unsigned short f2bf(float v) {
    union { float f; unsigned u; } c; c.f = v;
    unsigned lsb = (c.u >> 16) & 1u;
    c.u += 0x7fffu + lsb;
    return (unsigned short)(c.u >> 16);
}

// ---------------------------------------------------------------------------
// Kernel 0a: w_conv f32 -> bf16 with K-dim permutation (c,k) -> (k,c).
//   wb2[o][k*256 + c] = bf16(w[o][c*9 + k])
// ---------------------------------------------------------------------------
__global__ __launch_bounds__(256) void w2b_perm(
    const float* __restrict__ w, unsigned short* __restrict__ wb)
{
    int idx = blockIdx.x * 256 + threadIdx.x;     // o*2304 + k*256 + c
    int o  = idx / CK_;
    int kk = idx - o * CK_;
    int k  = kk >> 8;
    int c  = kk & 255;
    wb[idx] = f2bf(w[o * CK_ + c * KK_ + k]);
}

// ---------------------------------------------------------------------------
// Kernel 0b: plain f32 -> bf16 convert (w_offset)
// ---------------------------------------------------------------------------
__global__ __launch_bounds__(256) void w2b(
    const float* __restrict__ w, unsigned short* __restrict__ wb)
{
    int idx = blockIdx.x * 256 + threadIdx.x;
    wb[idx] = f2bf(w[idx]);
}

// ---------------------------------------------------------------------------
// Kernel 0c: NCHW -> NHWC transpose of x.  xt[b][p][c] = x[b][c][p]
// ---------------------------------------------------------------------------
__global__ __launch_bounds__(256) void transpose_x(
    const float* __restrict__ x, float* __restrict__ xt)
{
    __shared__ float tile[64][65];
    const int t = threadIdx.x;
    const int bid = blockIdx.x;
    const int b  = bid / (144 * 4);
    const int r  = bid - b * 576;
    const int pt = r >> 2, ct = r & 3;
    const int p0 = pt * 64, c0 = ct * 64;

    const int px = t & 63, g = t >> 6;
#pragma unroll
    for (int i = 0; i < 16; i++) {
        int cr = g + i * 4;
        tile[cr][px] = x[((size_t)b * CHI_ + c0 + cr) * HW_ + p0 + px];
    }
    __syncthreads();
    const int c = t & 63;
#pragma unroll
    for (int i = 0; i < 16; i++) {
        int pr = g + i * 4;
        xt[((size_t)b * HW_ + p0 + pr) * CHI_ + c0 + c] = tile[c][pr];
    }
}

// ---------------------------------------------------------------------------
// Kernel 1: offset conv as MFMA GEMM (UNCHANGED from known-good baseline).
// ---------------------------------------------------------------------------
__global__ __launch_bounds__(256) void offset_mfma(
    const float* __restrict__ x, const unsigned short* __restrict__ wob,
    const float* __restrict__ bo, float* __restrict__ om)
{
    __shared__ __align__(16) unsigned short s_w[32 * OPITCH_];     //  6656 B
    __shared__ __align__(16) unsigned short s_cols[OTPX_ * OPITCH_];// 13312 B

    const int t = threadIdx.x;
    const int pixtile = blockIdx.x % (HW_ / OTPX_);  // 144
    const int b       = blockIdx.x / (HW_ / OTPX_);  // 4
    const int p0 = pixtile * OTPX_;

    const int lane = t & 63, wave = t >> 6;
    const int quad = lane >> 4, l15 = lane & 15;

    const int i   = t & 63;            // pixel within tile (staging role)
    const int jlb = (t >> 6) * 24;     // k-subrange within chunk
    const int p   = p0 + i;
    const int h   = p / WW_, w = p % WW_;
    const float* xb = x + (size_t)b * CHI_ * HW_;

    f32x4 acc[2];
    acc[0] = (f32x4){0.f,0.f,0.f,0.f};
    acc[1] = (f32x4){0.f,0.f,0.f,0.f};

    for (int kc = 0; kc < CK_ / OKC_; kc++) {        // 24 chunks
        const int j0 = kc * OKC_;
        if (kc) __syncthreads();
#pragma unroll
        for (int n = 0; n < 3; n++) {
            int e = t + n * 256;                     // < 768
            int ocl = e / 24, kq = e % 24;
            uint2 v = make_uint2(0u, 0u);
            if (ocl < 27)
                v = *reinterpret_cast<const uint2*>(wob + (size_t)ocl * CK_ + j0 + kq * 4);
            *reinterpret_cast<uint2*>(&s_w[ocl * OPITCH_ + kq * 4]) = v;
        }
        union { unsigned short s[24]; uint4 q[3]; } pk;
#pragma unroll
        for (int m = 0; m < 24; m++) {
            int jg = j0 + jlb + m;
            int c  = (jg * 7282) >> 16;              // jg/9
            int k  = jg - 9 * c;
            int yy = h + k / 3 - 1, xx = w + k % 3 - 1;
            bool ok = ((unsigned)yy < HH_) & ((unsigned)xx < WW_);
            float v = ok ? xb[(size_t)c * HW_ + yy * WW_ + xx] : 0.f;
            pk.s[m] = f2bf(v);
        }
        {
            uint4* dst = reinterpret_cast<uint4*>(&s_cols[i * OPITCH_ + jlb]);
            dst[0] = pk.q[0]; dst[1] = pk.q[1]; dst[2] = pk.q[2];
        }
        __syncthreads();
#pragma unroll
        for (int ks = 0; ks < OKC_ / 32; ks++) {
            short8 a0 = *reinterpret_cast<const short8*>(
                &s_w[(l15) * OPITCH_ + ks * 32 + quad * 8]);
            short8 a1 = *reinterpret_cast<const short8*>(
                &s_w[(16 + l15) * OPITCH_ + ks * 32 + quad * 8]);
            short8 b0 = *reinterpret_cast<const short8*>(
                &s_cols[(wave * 16 + l15) * OPITCH_ + ks * 32 + quad * 8]);
            acc[0] = __builtin_amdgcn_mfma_f32_16x16x32_bf16(a0, b0, acc[0], 0, 0, 0);
            acc[1] = __builtin_amdgcn_mfma_f32_16x16x32_bf16(a1, b0, acc[1], 0, 0, 0);
        }
    }

#pragma unroll
    for (int mt = 0; mt < 2; mt++) {
#pragma unroll
        for (int r = 0; r < 4; r++) {
            int oc = mt * 16 + quad * 4 + r;
            if (oc < 27) {
                int pix = p0 + wave * 16 + l15;
                om[((size_t)b * 27 + oc) * HW_ + pix] = acc[mt][r] + bo[oc];
            }
        }
    }
}

// ---------------------------------------------------------------------------
// Kernel 2: fused channels-last gather + bf16 MFMA GEMM (px-split).
//   Block: 256 oc x 32 px, 1152 blocks. Chunk kc (36) = tap kc>>2, 64 ch.
//   B-stage: thread = 1 px x 8 ch -> 8 coalesced float4 loads. A-stage,
//   swizzle, MFMA, epilogue = R7-proven formulas (px width halved).
// ---------------------------------------------------------------------------
__global__ __launch_bounds__(256, 4) void deform_fused(
    const float* __restrict__ xt, const float* __restrict__ om,
    const unsigned short* __restrict__ wb, const float* __restrict__ bconv,
    float* __restrict__ outb)
{
    __shared__ __align__(16) unsigned short sA[CHO_ * 64];   // 32768 B (swizzled)
    __shared__ __align__(16) unsigned short sB[32 * 64];     //  4096 B (swizzled)
    __shared__ float s_py[KK_ * 32], s_px[KK_ * 32], s_mask[KK_ * 32]; // 3456 B

    const int t = threadIdx.x;
    // XCD-aware: 1152 = 8 XCDs x 144 contiguous (b, 32-px tile) units
    const int bid = blockIdx.x;
    const int u   = (bid & 7) * 144 + (bid >> 3);    // [0,1152)
    const int pixtile = u % 288;
    const int b       = u / 288;
    const int p0 = pixtile * 32;

    // ---- meta: py/px/mask for 9 taps x 32 pixels (once per block) ----
    for (int e = t; e < KK_ * 32; e += 256) {
        int k = e >> 5, i = e & 31;
        int p = p0 + i;
        int h = p / WW_, w = p % WW_;
        const float* omb = om + ((size_t)b * 27) * HW_ + p;
        float dy = omb[(2 * k) * HW_];
        float dx = omb[(2 * k + 1) * HW_];
        float m  = omb[(18 + k) * HW_];
        s_py[e]   = dy + (float)(h + k / 3 - 1);
        s_px[e]   = dx + (float)(w + (k % 3) - 1);
        s_mask[e] = 1.f / (1.f + __expf(-m));
    }

    const int lane = t & 63, wave = t >> 6;
    const int quad = lane >> 4, l15 = lane & 15;
    const int pxl  = t >> 3;           // gather role: pixel 0..31
    const int cg   = t & 7;            // gather role: 8-ch group

    f32x4 acc[4][2];
#pragma unroll
    for (int m = 0; m < 4; m++)
#pragma unroll
        for (int n = 0; n < 2; n++)
            acc[m][n] = (f32x4){0.f, 0.f, 0.f, 0.f};

    const float* xtb = xt + (size_t)b * HW_ * CHI_;
    char* sAb = (char*)sA;
    char* sBb = (char*)sB;

    __syncthreads();   // meta visible

    for (int kc = 0; kc < 36; kc++) {
        const int j0 = kc * 64;
        if (kc) __syncthreads();
        // ---- stage A (W'): 256 oc x 64 kk, 8 x uint4 per thread, swizzled
#pragma unroll
        for (int n = 0; n < 8; n++) {
            int e = t + n * 256;                   // < 2048
            int ocl = e >> 3, ko = e & 7;
            uint4 v = *reinterpret_cast<const uint4*>(
                wb + (size_t)ocl * CK_ + j0 + ko * 8);
            *reinterpret_cast<uint4*>(
                sAb + (ocl << 7) + ((ko << 4) ^ ((ocl & 7) << 4))) = v;
        }
        // ---- stage B: gather 32 px x 64 ch for tap k (coalesced) ----
        {
            const int k  = kc >> 2;
            const int c0 = (kc & 3) << 6;
            const int e  = k * 32 + pxl;
            float py = s_py[e], pxx = s_px[e], msk = s_mask[e];
            float y0f = floorf(py), x0f = floorf(pxx);
            float ly = py - y0f, lx = pxx - x0f;
            int y0 = (int)y0f, x0 = (int)x0f;
            float vy0 = ((unsigned)y0       < HH_) ? 1.f : 0.f;
            float vy1 = ((unsigned)(y0 + 1) < HH_) ? 1.f : 0.f;
            float vx0 = ((unsigned)x0       < WW_) ? 1.f : 0.f;
            float vx1 = ((unsigned)(x0 + 1) < WW_) ? 1.f : 0.f;
            int yc0 = min(max(y0, 0), HH_ - 1), yc1 = min(max(y0 + 1, 0), HH_ - 1);
            int xc0 = min(max(x0, 0), WW_ - 1), xc1 = min(max(x0 + 1, 0), WW_ - 1);
            float wy0 = 1.f - ly, wx0 = 1.f - lx;
            float w00 = wy0 * wx0 * vy0 * vx0 * msk;
            float w01 = wy0 * lx  * vy0 * vx1 * msk;
            float w10 = ly  * wx0 * vy1 * vx0 * msk;
            float w11 = ly  * lx  * vy1 * vx1 * msk;
            const float* base = xtb + c0 + cg * 8;
            const float4* r00 = reinterpret_cast<const float4*>(
                base + (size_t)(yc0 * WW_ + xc0) * CHI_);
            const float4* r01 = reinterpret_cast<const float4*>(
                base + (size_t)(yc0 * WW_ + xc1) * CHI_);
            const float4* r10 = reinterpret_cast<const float4*>(
                base + (size_t)(yc1 * WW_ + xc0) * CHI_);
            const float4* r11 = reinterpret_cast<const float4*>(
                base + (size_t)(yc1 * WW_ + xc1) * CHI_);
            union { unsigned short s[8]; uint4 q; } pk;
#pragma unroll
            for (int i = 0; i < 2; i++) {
                float4 fa = r00[i], fb = r01[i], fc = r10[i], fd = r11[i];
                pk.s[i * 4 + 0] = f2bf(fa.x * w00 + fb.x * w01 + fc.x * w10 + fd.x * w11);
                pk.s[i * 4 + 1] = f2bf(fa.y * w00 + fb.y * w01 + fc.y * w10 + fd.y * w11);
                pk.s[i * 4 + 2] = f2bf(fa.z * w00 + fb.z * w01 + fc.z * w10 + fd.z * w11);
                pk.s[i * 4 + 3] = f2bf(fa.w * w00 + fb.w * w01 + fc.w * w10 + fd.w * w11);
            }
            *reinterpret_cast<uint4*>(
                sBb + (pxl << 7) + ((cg << 4) ^ ((pxl & 7) << 4))) = pk.q;
        }
        __syncthreads();
        // ---- MFMA: 2 K-steps of 32; wave = 64-oc slice, 32 px ----
#pragma unroll
        for (int ks = 0; ks < 2; ks++) {
            short8 afr[4], bfr[2];
#pragma unroll
            for (int m = 0; m < 4; m++) {
                int r = wave * 64 + m * 16 + l15;
                afr[m] = *reinterpret_cast<const short8*>(
                    sAb + (r << 7) + (((ks << 6) + (quad << 4)) ^ ((r & 7) << 4)));
            }
#pragma unroll
            for (int n = 0; n < 2; n++) {
                int r = n * 16 + l15;
                bfr[n] = *reinterpret_cast<const short8*>(
                    sBb + (r << 7) + (((ks << 6) + (quad << 4)) ^ ((r & 7) << 4)));
            }
#pragma unroll
            for (int m = 0; m < 4; m++)
#pragma unroll
                for (int n = 0; n < 2; n++)
                    acc[m][n] = __builtin_amdgcn_mfma_f32_16x16x32_bf16(
                        afr[m], bfr[n], acc[m][n], 0, 0, 0);
        }
    }

    // ---- epilogue: C/D layout col=lane&15 (pixel), row=quad*4+r (oc) ----
#pragma unroll
    for (int m = 0; m < 4; m++) {
#pragma unroll
        for (int n = 0; n < 2; n++) {
#pragma unroll
            for (int r = 0; r < 4; r++) {
                int oc  = wave * 64 + m * 16 + quad * 4 + r;
                int pix = p0 + n * 16 + l15;
                outb[((size_t)b * CHO_ + oc) * HW_ + pix] = acc[m][n][r] + bconv[oc];
            }
        }
    }
}

// ---------------------------------------------------------------------------
// Kernel 3: BN statistics (sum, sumsq) per channel, deterministic two-pass
// ---------------------------------------------------------------------------
__global__ __launch_bounds__(256) void bn_stats(
    const float* __restrict__ outb, float* __restrict__ stats)
{
    int o = blockIdx.x, t = threadIdx.x;
    float s = 0.f, s2 = 0.f;
    for (int b = 0; b < BN_; b++) {
        const float* base = outb + ((size_t)b * CHO_ + o) * HW_;
        for (int p = t; p < HW_; p += 256) {
            float v = base[p];
            s += v; s2 += v * v;
        }
    }
#pragma unroll
    for (int off = 32; off > 0; off >>= 1) {
        s  += __shfl_down(s,  off, 64);
        s2 += __shfl_down(s2, off, 64);
    }
    __shared__ float rs[4], rs2[4];
    int lane = t & 63, wv = t >> 6;
    if (lane == 0) { rs[wv] = s; rs2[wv] = s2; }
    __syncthreads();
    if (t == 0) {
        stats[o]        = rs[0] + rs[1] + rs[2] + rs[3];
        stats[CHO_ + o] = rs2[0] + rs2[1] + rs2[2] + rs2[3];
    }
}

// ---------------------------------------------------------------------------
// Kernel 4: BN apply + ReLU, f32 out
// ---------------------------------------------------------------------------
__global__ __launch_bounds__(256) void bn_apply(
    const float* __restrict__ outb, const float* __restrict__ stats,
    const float* __restrict__ gamma, const float* __restrict__ beta,
    float* __restrict__ y)
{
    int idx = blockIdx.x * 256 + threadIdx.x;
    size_t i0 = (size_t)idx * 4;                  // < 9437184
    int o = (int)((i0 / HW_) % CHO_);
    float4 v = *reinterpret_cast<const float4*>(outb + i0);
    const float invN = 1.f / (float)NRED_;
    float mu  = stats[o] * invN;
    float var = stats[CHO_ + o] * invN - mu * mu;
    float inv = rsqrtf(var + BN_EPS_);
    float sc = gamma[o] * inv;
    float sh = beta[o] - mu * sc;
    float4 r;
    r.x = fmaxf(v.x * sc + sh, 0.f);
    r.y = fmaxf(v.y * sc + sh, 0.f);
    r.z = fmaxf(v.z * sc + sh, 0.f);
    r.w = fmaxf(v.w * sc + sh, 0.f);
    *reinterpret_cast<float4*>(y + i0) = r;
}

// ---------------------------------------------------------------------------
extern "C" void kernel_launch(void* const* d_in, const int* in_sizes, int n_in,
                              void* d_out, int out_size, void* d_ws, size_t ws_size,
                              hipStream_t stream)
{
    const float* x   = (const float*)d_in[0];
    const float* wof = (const float*)d_in[1];
    const float* bof = (const float*)d_in[2];
    const float* wcv = (const float*)d_in[3];
    const float* bcv = (const float*)d_in[4];
    const float* gam = (const float*)d_in[5];
    const float* bet = (const float*)d_in[6];
    float* y = (float*)d_out;

    char* ws = (char*)d_ws;
    float*          om    = (float*)ws;                                   // 3.98 MB
    float*          outb  = (float*)(ws + (size_t)4 * 1024 * 1024);       // 36 MB
    float*          stats = (float*)(ws + (size_t)40 * 1024 * 1024);      // 2 KB
    unsigned short* wbf2  = (unsigned short*)(ws + (size_t)40 * 1024 * 1024 + 8192);            // 1.125 MB
    unsigned short* wob   = (unsigned short*)(ws + (size_t)40 * 1024 * 1024 + 8192 + 1179648);  // 121.5 KB
    float*          xt    = (float*)(ws + (size_t)44 * 1024 * 1024);      // 37.75 MB

    w2b_perm<<<(CHO_ * CK_) / 256, 256, 0, stream>>>(wcv, wbf2);  // 2304 blocks
    w2b<<<(27 * CK_) / 256, 256, 0, stream>>>(wof, wob);          // 243 blocks
    transpose_x<<<BN_ * 144 * 4, 256, 0, stream>>>(x, xt);        // 2304 blocks
    offset_mfma<<<BN_ * (HW_ / OTPX_), 256, 0, stream>>>(x, wob, bof, om);
    deform_fused<<<BN_ * 2 * (HW_ / 64), 256, 0, stream>>>(xt, om, wbf2, bcv, outb);
    bn_stats<<<CHO_, 256, 0, stream>>>(outb, stats);
    bn_apply<<<(BN_ * CHO_ * HW_) / (4 * 256), 256, 0, stream>>>(outb, stats, gam, bet, y);
}

// Round 12
// 297.260 us; speedup vs baseline: 1.5201x; 1.2136x over previous
//
#include <hip/hip_runtime.h>
#include <math.h>

// Problem constants (DeformConv_68109591380935) — ALL TENSORS FLOAT32
#define BN_    4
#define CHI_   256
#define CHO_   256
#define HH_    96
#define WW_    96
#define HW_    (HH_*WW_)        // 9216
#define KK_    9
#define CK_    (CHI_*KK_)       // 2304
#define NRED_  (BN_*HW_)        // 36864 samples per BN channel
#define BN_EPS_ 1e-5f

// R11: offset conv rewritten channels-last (offset_nhwc): chunk = tap x 64ch,
// B-stage = coalesced shifted-row load from xt (deform_fused's B minus the
// bilinear). bn_stats split 256 -> 2048 blocks + deterministic reduce.
// deform_fused = R9/R10-proven (133 us) UNCHANGED.

typedef short short8 __attribute__((ext_vector_type(8)));
typedef float f32x4  __attribute__((ext_vector_type(4)));

// round-to-nearest-even f32 -> bf16 bit pattern
__device__ __forceinline__ unsigned short f2bf(float v) {
    union { float f; unsigned u; } c; c.f = v;
    unsigned lsb = (c.u >> 16) & 1u;
    c.u += 0x7fffu + lsb;
    return (unsigned short)(c.u >> 16);
}

// ---------------------------------------------------------------------------
// Kernel 0a: w_conv f32 -> bf16 with K-dim permutation (c,k) -> (k,c).
//   wb2[o][k*256 + c] = bf16(w[o][c*9 + k])
// ---------------------------------------------------------------------------
__global__ __launch_bounds__(256) void w2b_perm(
    const float* __restrict__ w, unsigned short* __restrict__ wb)
{
    int idx = blockIdx.x * 256 + threadIdx.x;     // o*2304 + k*256 + c
    int o  = idx / CK_;
    int kk = idx - o * CK_;
    int k  = kk >> 8;
    int c  = kk & 255;
    wb[idx] = f2bf(w[o * CK_ + c * KK_ + k]);
}

// ---------------------------------------------------------------------------
// Kernel 0b: w_offset f32 -> bf16, kk-major permutation (27 rows).
// ---------------------------------------------------------------------------
__global__ __launch_bounds__(256) void w2b_perm27(
    const float* __restrict__ w, unsigned short* __restrict__ wb)
{
    int idx = blockIdx.x * 256 + threadIdx.x;     // < 27*2304 = 62208
    int o  = idx / CK_;
    int kk = idx - o * CK_;
    int k  = kk >> 8;
    int c  = kk & 255;
    wb[idx] = f2bf(w[o * CK_ + c * KK_ + k]);
}

// ---------------------------------------------------------------------------
// Kernel 0c: NCHW -> NHWC transpose of x.  xt[b][p][c] = x[b][c][p]
// ---------------------------------------------------------------------------
__global__ __launch_bounds__(256) void transpose_x(
    const float* __restrict__ x, float* __restrict__ xt)
{
    __shared__ float tile[64][65];
    const int t = threadIdx.x;
    const int bid = blockIdx.x;
    const int b  = bid / (144 * 4);
    const int r  = bid - b * 576;
    const int pt = r >> 2, ct = r & 3;
    const int p0 = pt * 64, c0 = ct * 64;

    const int px = t & 63, g = t >> 6;
#pragma unroll
    for (int i = 0; i < 16; i++) {
        int cr = g + i * 4;
        tile[cr][px] = x[((size_t)b * CHI_ + c0 + cr) * HW_ + p0 + px];
    }
    __syncthreads();
    const int c = t & 63;
#pragma unroll
    for (int i = 0; i < 16; i++) {
        int pr = g + i * 4;
        xt[((size_t)b * HW_ + p0 + pr) * CHI_ + c0 + c] = tile[c][pr];
    }
}

// ---------------------------------------------------------------------------
// Kernel 1: offset conv as channels-last MFMA GEMM.
//   om[b, 27, HW] = Woff'[27, kk] x im2col_nhwc(xt)  + b_offset
//   Block: 32 oc (27 real) x 64 px, 576 blocks. Chunk kc (36) = tap kc>>2,
//   64 ch. B-stage = ONE shifted-row coalesced load (no bilinear).
// ---------------------------------------------------------------------------
__global__ __launch_bounds__(256) void offset_nhwc(
    const float* __restrict__ xt, const unsigned short* __restrict__ wob,
    const float* __restrict__ bo, float* __restrict__ om)
{
    __shared__ __align__(16) unsigned short sW[32 * 64];   // 4096 B (swizzled)
    __shared__ __align__(16) unsigned short sB[64 * 64];   // 8192 B (swizzled)

    const int t = threadIdx.x;
    const int bid = blockIdx.x;
    const int u   = (bid & 7) * 72 + (bid >> 3);     // [0,576)
    const int pixtile = u % 144;
    const int b       = u / 144;
    const int p0 = pixtile * 64;

    const int lane = t & 63, wave = t >> 6;
    const int quad = lane >> 4, l15 = lane & 15;
    const int pxl  = t >> 2;           // B-stage: pixel 0..63
    const int cg   = t & 3;            // B-stage: 16-ch group
    const int aro  = t >> 3;           // A-stage: oc row 0..31
    const int ako  = t & 7;            // A-stage: 8-k group

    f32x4 acc[2];
    acc[0] = (f32x4){0.f,0.f,0.f,0.f};
    acc[1] = (f32x4){0.f,0.f,0.f,0.f};

    const float* xtb = xt + (size_t)b * HW_ * CHI_;
    char* sWb = (char*)sW;
    char* sBb = (char*)sB;

    // pixel coords for B-stage role (constant over chunks)
    const int p = p0 + pxl;
    const int h = p / WW_, w = p % WW_;

    for (int kc = 0; kc < 36; kc++) {
        if (kc) __syncthreads();
        // ---- stage A (Woff'): 32 oc x 64 kk, 1 uint4/thread, rows>=27 zero
        {
            uint4 v = make_uint4(0u, 0u, 0u, 0u);
            if (aro < 27)
                v = *reinterpret_cast<const uint4*>(
                    wob + (size_t)aro * CK_ + kc * 64 + ako * 8);
            *reinterpret_cast<uint4*>(
                sWb + (aro << 7) + ((ako << 4) ^ ((aro & 7) << 4))) = v;
        }
        // ---- stage B: 64 px x 64 ch shifted-row load (coalesced) ----
        {
            const int k  = kc >> 2;
            const int c0 = (kc & 3) << 6;
            const int yy = h + k / 3 - 1;
            const int xx = w + (k % 3) - 1;
            const bool ok = ((unsigned)yy < HH_) & ((unsigned)xx < WW_);
            union { unsigned short s[16]; uint4 q[2]; } pk;
            if (ok) {
                const float4* src = reinterpret_cast<const float4*>(
                    xtb + (size_t)(yy * WW_ + xx) * CHI_ + c0 + cg * 16);
#pragma unroll
                for (int i = 0; i < 4; i++) {
                    float4 f = src[i];
                    pk.s[i * 4 + 0] = f2bf(f.x);
                    pk.s[i * 4 + 1] = f2bf(f.y);
                    pk.s[i * 4 + 2] = f2bf(f.z);
                    pk.s[i * 4 + 3] = f2bf(f.w);
                }
            } else {
                pk.q[0] = make_uint4(0u, 0u, 0u, 0u);
                pk.q[1] = make_uint4(0u, 0u, 0u, 0u);
            }
            const int u0 = cg << 1;
            *reinterpret_cast<uint4*>(
                sBb + (pxl << 7) + ((u0 << 4) ^ ((pxl & 7) << 4))) = pk.q[0];
            *reinterpret_cast<uint4*>(
                sBb + (pxl << 7) + (((u0 + 1) << 4) ^ ((pxl & 7) << 4))) = pk.q[1];
        }
        __syncthreads();
        // ---- MFMA: 2 K-steps; A = 2 oc-tiles, B = wave's pixel quarter ----
#pragma unroll
        for (int ks = 0; ks < 2; ks++) {
            short8 a0, a1, b0;
            {
                int r = l15;
                a0 = *reinterpret_cast<const short8*>(
                    sWb + (r << 7) + (((ks << 6) + (quad << 4)) ^ ((r & 7) << 4)));
                r = 16 + l15;
                a1 = *reinterpret_cast<const short8*>(
                    sWb + (r << 7) + (((ks << 6) + (quad << 4)) ^ ((r & 7) << 4)));
                r = wave * 16 + l15;
                b0 = *reinterpret_cast<const short8*>(
                    sBb + (r << 7) + (((ks << 6) + (quad << 4)) ^ ((r & 7) << 4)));
            }
            acc[0] = __builtin_amdgcn_mfma_f32_16x16x32_bf16(a0, b0, acc[0], 0, 0, 0);
            acc[1] = __builtin_amdgcn_mfma_f32_16x16x32_bf16(a1, b0, acc[1], 0, 0, 0);
        }
    }

    // epilogue: C/D layout col=lane&15 (pixel), row=quad*4+r (oc)
#pragma unroll
    for (int mt = 0; mt < 2; mt++) {
#pragma unroll
        for (int r = 0; r < 4; r++) {
            int oc = mt * 16 + quad * 4 + r;
            if (oc < 27) {
                int pix = p0 + wave * 16 + l15;
                om[((size_t)b * 27 + oc) * HW_ + pix] = acc[mt][r] + bo[oc];
            }
        }
    }
}

// ---------------------------------------------------------------------------
// Kernel 2: fused channels-last gather + bf16 MFMA GEMM (px-split).
//   UNCHANGED from R9/R10 (proven 133 us).
// ---------------------------------------------------------------------------
__global__ __launch_bounds__(256, 4) void deform_fused(
    const float* __restrict__ xt, const float* __restrict__ om,
    const unsigned short* __restrict__ wb, const float* __restrict__ bconv,
    float* __restrict__ outb)
{
    __shared__ __align__(16) unsigned short sA[CHO_ * 64];   // 32768 B (swizzled)
    __shared__ __align__(16) unsigned short sB[32 * 64];     //  4096 B (swizzled)
    __shared__ float s_py[KK_ * 32], s_px[KK_ * 32], s_mask[KK_ * 32]; // 3456 B

    const int t = threadIdx.x;
    const int bid = blockIdx.x;
    const int u   = (bid & 7) * 144 + (bid >> 3);    // [0,1152)
    const int pixtile = u % 288;
    const int b       = u / 288;
    const int p0 = pixtile * 32;

    for (int e = t; e < KK_ * 32; e += 256) {
        int k = e >> 5, i = e & 31;
        int p = p0 + i;
        int h = p / WW_, w = p % WW_;
        const float* omb = om + ((size_t)b * 27) * HW_ + p;
        float dy = omb[(2 * k) * HW_];
        float dx = omb[(2 * k + 1) * HW_];
        float m  = omb[(18 + k) * HW_];
        s_py[e]   = dy + (float)(h + k / 3 - 1);
        s_px[e]   = dx + (float)(w + (k % 3) - 1);
        s_mask[e] = 1.f / (1.f + __expf(-m));
    }

    const int lane = t & 63, wave = t >> 6;
    const int quad = lane >> 4, l15 = lane & 15;
    const int pxl  = t >> 3;           // gather role: pixel 0..31
    const int cg   = t & 7;            // gather role: 8-ch group

    f32x4 acc[4][2];
#pragma unroll
    for (int m = 0; m < 4; m++)
#pragma unroll
        for (int n = 0; n < 2; n++)
            acc[m][n] = (f32x4){0.f, 0.f, 0.f, 0.f};

    const float* xtb = xt + (size_t)b * HW_ * CHI_;
    char* sAb = (char*)sA;
    char* sBb = (char*)sB;

    __syncthreads();   // meta visible

    for (int kc = 0; kc < 36; kc++) {
        const int j0 = kc * 64;
        if (kc) __syncthreads();
#pragma unroll
        for (int n = 0; n < 8; n++) {
            int e = t + n * 256;                   // < 2048
            int ocl = e >> 3, ko = e & 7;
            uint4 v = *reinterpret_cast<const uint4*>(
                wb + (size_t)ocl * CK_ + j0 + ko * 8);
            *reinterpret_cast<uint4*>(
                sAb + (ocl << 7) + ((ko << 4) ^ ((ocl & 7) << 4))) = v;
        }
        {
            const int k  = kc >> 2;
            const int c0 = (kc & 3) << 6;
            const int e  = k * 32 + pxl;
            float py = s_py[e], pxx = s_px[e], msk = s_mask[e];
            float y0f = floorf(py), x0f = floorf(pxx);
            float ly = py - y0f, lx = pxx - x0f;
            int y0 = (int)y0f, x0 = (int)x0f;
            float vy0 = ((unsigned)y0       < HH_) ? 1.f : 0.f;
            float vy1 = ((unsigned)(y0 + 1) < HH_) ? 1.f : 0.f;
            float vx0 = ((unsigned)x0       < WW_) ? 1.f : 0.f;
            float vx1 = ((unsigned)(x0 + 1) < WW_) ? 1.f : 0.f;
            int yc0 = min(max(y0, 0), HH_ - 1), yc1 = min(max(y0 + 1, 0), HH_ - 1);
            int xc0 = min(max(x0, 0), WW_ - 1), xc1 = min(max(x0 + 1, 0), WW_ - 1);
            float wy0 = 1.f - ly, wx0 = 1.f - lx;
            float w00 = wy0 * wx0 * vy0 * vx0 * msk;
            float w01 = wy0 * lx  * vy0 * vx1 * msk;
            float w10 = ly  * wx0 * vy1 * vx0 * msk;
            float w11 = ly  * lx  * vy1 * vx1 * msk;
            const float* base = xtb + c0 + cg * 8;
            const float4* r00 = reinterpret_cast<const float4*>(
                base + (size_t)(yc0 * WW_ + xc0) * CHI_);
            const float4* r01 = reinterpret_cast<const float4*>(
                base + (size_t)(yc0 * WW_ + xc1) * CHI_);
            const float4* r10 = reinterpret_cast<const float4*>(
                base + (size_t)(yc1 * WW_ + xc0) * CHI_);
            const float4* r11 = reinterpret_cast<const float4*>(
                base + (size_t)(yc1 * WW_ + xc1) * CHI_);
            union { unsigned short s[8]; uint4 q; } pk;
#pragma unroll
            for (int i = 0; i < 2; i++) {
                float4 fa = r00[i], fb = r01[i], fc = r10[i], fd = r11[i];
                pk.s[i * 4 + 0] = f2bf(fa.x * w00 + fb.x * w01 + fc.x * w10 + fd.x * w11);
                pk.s[i * 4 + 1] = f2bf(fa.y * w00 + fb.y * w01 + fc.y * w10 + fd.y * w11);
                pk.s[i * 4 + 2] = f2bf(fa.z * w00 + fb.z * w01 + fc.z * w10 + fd.z * w11);
                pk.s[i * 4 + 3] = f2bf(fa.w * w00 + fb.w * w01 + fc.w * w10 + fd.w * w11);
            }
            *reinterpret_cast<uint4*>(
                sBb + (pxl << 7) + ((cg << 4) ^ ((pxl & 7) << 4))) = pk.q;
        }
        __syncthreads();
#pragma unroll
        for (int ks = 0; ks < 2; ks++) {
            short8 afr[4], bfr[2];
#pragma unroll
            for (int m = 0; m < 4; m++) {
                int r = wave * 64 + m * 16 + l15;
                afr[m] = *reinterpret_cast<const short8*>(
                    sAb + (r << 7) + (((ks << 6) + (quad << 4)) ^ ((r & 7) << 4)));
            }
#pragma unroll
            for (int n = 0; n < 2; n++) {
                int r = n * 16 + l15;
                bfr[n] = *reinterpret_cast<const short8*>(
                    sBb + (r << 7) + (((ks << 6) + (quad << 4)) ^ ((r & 7) << 4)));
            }
#pragma unroll
            for (int m = 0; m < 4; m++)
#pragma unroll
                for (int n = 0; n < 2; n++)
                    acc[m][n] = __builtin_amdgcn_mfma_f32_16x16x32_bf16(
                        afr[m], bfr[n], acc[m][n], 0, 0, 0);
        }
    }

#pragma unroll
    for (int m = 0; m < 4; m++) {
#pragma unroll
        for (int n = 0; n < 2; n++) {
#pragma unroll
            for (int r = 0; r < 4; r++) {
                int oc  = wave * 64 + m * 16 + quad * 4 + r;
                int pix = p0 + n * 16 + l15;
                outb[((size_t)b * CHO_ + oc) * HW_ + pix] = acc[m][n][r] + bconv[oc];
            }
        }
    }
}

// ---------------------------------------------------------------------------
// Kernel 3a: BN partial stats. 2048 blocks = channel x 8 slices, float4 loads.
// ---------------------------------------------------------------------------
__global__ __launch_bounds__(256) void bn_stats_part(
    const float* __restrict__ outb, float* __restrict__ part)
{
    const int bid = blockIdx.x;            // 2048
    const int o = bid >> 3, sl = bid & 7;
    const int t = threadIdx.x;
    float s = 0.f, s2 = 0.f;
    for (int b = 0; b < BN_; b++) {
        const float4* base = reinterpret_cast<const float4*>(
            outb + ((size_t)b * CHO_ + o) * HW_ + sl * 1152);
        for (int i = t; i < 288; i += 256) {     // 288 float4 = 1152 floats
            float4 v = base[i];
            s  += v.x + v.y + v.z + v.w;
            s2 += v.x * v.x + v.y * v.y + v.z * v.z + v.w * v.w;
        }
    }
#pragma unroll
    for (int off = 32; off > 0; off >>= 1) {
        s  += __shfl_down(s,  off, 64);
        s2 += __shfl_down(s2, off, 64);
    }
    __shared__ float rs[4], rs2[4];
    int lane = t & 63, wv = t >> 6;
    if (lane == 0) { rs[wv] = s; rs2[wv] = s2; }
    __syncthreads();
    if (t == 0) {
        part[o * 8 + sl]                = rs[0] + rs[1] + rs[2] + rs[3];
        part[CHO_ * 8 + o * 8 + sl]     = rs2[0] + rs2[1] + rs2[2] + rs2[3];
    }
}

// ---------------------------------------------------------------------------
// Kernel 3b: deterministic reduce of 8 partials per channel.
// ---------------------------------------------------------------------------
__global__ __launch_bounds__(256) void bn_reduce(
    const float* __restrict__ part, float* __restrict__ stats)
{
    int o = threadIdx.x;                   // one block of 256
    float s = 0.f, s2 = 0.f;
#pragma unroll
    for (int i = 0; i < 8; i++) {
        s  += part[o * 8 + i];
        s2 += part[CHO_ * 8 + o * 8 + i];
    }
    stats[o]        = s;
    stats[CHO_ + o] = s2;
}

// ---------------------------------------------------------------------------
// Kernel 4: BN apply + ReLU, f32 out
// ---------------------------------------------------------------------------
__global__ __launch_bounds__(256) void bn_apply(
    const float* __restrict__ outb, const float* __restrict__ stats,
    const float* __restrict__ gamma, const float* __restrict__ beta,
    float* __restrict__ y)
{
    int idx = blockIdx.x * 256 + threadIdx.x;
    size_t i0 = (size_t)idx * 4;                  // < 9437184
    int o = (int)((i0 / HW_) % CHO_);
    float4 v = *reinterpret_cast<const float4*>(outb + i0);
    const float invN = 1.f / (float)NRED_;
    float mu  = stats[o] * invN;
    float var = stats[CHO_ + o] * invN - mu * mu;
    float inv = rsqrtf(var + BN_EPS_);
    float sc = gamma[o] * inv;
    float sh = beta[o] - mu * sc;
    float4 r;
    r.x = fmaxf(v.x * sc + sh, 0.f);
    r.y = fmaxf(v.y * sc + sh, 0.f);
    r.z = fmaxf(v.z * sc + sh, 0.f);
    r.w = fmaxf(v.w * sc + sh, 0.f);
    *reinterpret_cast<float4*>(y + i0) = r;
}

// ---------------------------------------------------------------------------
extern "C" void kernel_launch(void* const* d_in, const int* in_sizes, int n_in,
                              void* d_out, int out_size, void* d_ws, size_t ws_size,
                              hipStream_t stream)
{
    const float* x   = (const float*)d_in[0];
    const float* wof = (const float*)d_in[1];
    const float* bof = (const float*)d_in[2];
    const float* wcv = (const float*)d_in[3];
    const float* bcv = (const float*)d_in[4];
    const float* gam = (const float*)d_in[5];
    const float* bet = (const float*)d_in[6];
    float* y = (float*)d_out;

    char* ws = (char*)d_ws;
    float*          om    = (float*)ws;                                   // 3.98 MB
    float*          outb  = (float*)(ws + (size_t)4 * 1024 * 1024);       // 36 MB
    float*          stats = (float*)(ws + (size_t)40 * 1024 * 1024);      // 2 KB
    unsigned short* wbf2  = (unsigned short*)(ws + (size_t)40 * 1024 * 1024 + 8192);            // 1.125 MB
    unsigned short* wob   = (unsigned short*)(ws + (size_t)40 * 1024 * 1024 + 8192 + 1179648);  // 121.5 KB
    float*          xt    = (float*)(ws + (size_t)44 * 1024 * 1024);      // 37.75 MB
    float*          part  = (float*)(ws + (size_t)82 * 1024 * 1024);      // 16 KB

    w2b_perm<<<(CHO_ * CK_) / 256, 256, 0, stream>>>(wcv, wbf2);  // 2304 blocks
    w2b_perm27<<<(27 * CK_) / 256, 256, 0, stream>>>(wof, wob);   // 243 blocks
    transpose_x<<<BN_ * 144 * 4, 256, 0, stream>>>(x, xt);        // 2304 blocks
    offset_nhwc<<<BN_ * 144, 256, 0, stream>>>(xt, wob, bof, om); // 576 blocks
    deform_fused<<<BN_ * 2 * (HW_ / 64), 256, 0, stream>>>(xt, om, wbf2, bcv, outb);
    bn_stats_part<<<CHO_ * 8, 256, 0, stream>>>(outb, part);      // 2048 blocks
    bn_reduce<<<1, 256, 0, stream>>>(part, stats);
    bn_apply<<<(BN_ * CHO_ * HW_) / (4 * 256), 256, 0, stream>>>(outb, stats, gam, bet, y);
}